// Round 10
// baseline (2670.513 us; speedup 1.0000x reference)
//
#include <hip/hip_runtime.h>
#include <math.h>

#define N1 100000
#define N2 20000
#define EMB 128
#define NH 8
#define TILE 64
#define LPAD 132   // LDS row pitch (floats): 132 ≡ 4 (mod 32) banks, 16B-aligned
#define FEAT_BLKS ((N1 + TILE - 1) / TILE)   // 1563
#define MLPB1 ((N1 + TILE - 1) / TILE)       // 1563
#define MLPB2 ((N2 + TILE - 1) / TILE)       // 313

static constexpr float NEG = 0.2f;

// compile-time float4 component select (c must be a constant after unroll)
#define F4C(v, c) ((c) == 0 ? (v).x : (c) == 1 ? (v).y : (c) == 2 ? (v).z : (v).w)

// ---------------------------------------------------------------------------
// k_featcnt: fused kernel.
//   blocks [0, FEAT_BLKS): 64-row tile dual GEMM fs0 = h@W0, fs3 = h@W3,
//     512 threads, 4 rows x (4+4) cols per thread, software-pipelined weight
//     loads, fused attention-dot epilogue (el0/er0/el3).
//   blocks [FEAT_BLKS, ...): CSR degree count for the combined dst domain
//     (independent work overlapped with the GEMM).
// ---------------------------------------------------------------------------
__global__ __launch_bounds__(512) void k_featcnt(
    const float* __restrict__ item_emb, const int* __restrict__ item_ids,
    const float* __restrict__ fc_w, const float* __restrict__ attn_l,
    const float* __restrict__ attn_r,
    float* __restrict__ fs0, float* __restrict__ fs3,
    float* __restrict__ el0, float* __restrict__ er0, float* __restrict__ el3,
    const int* __restrict__ s1d, int nE1,
    const int* __restrict__ u1d, int nE3, int* __restrict__ cnt)
{
    __shared__ float xs[TILE][LPAD];   // 33.8 KB

    const int tid = threadIdx.x;

    if (blockIdx.x >= FEAT_BLKS) {
        // ---- CSR count part (no syncs, returns early; block-uniform) ----
        int i = (blockIdx.x - FEAT_BLKS) * 512 + tid;
        if (i < nE1) atomicAdd(&cnt[s1d[i]], 1);
        else if (i < nE1 + nE3) atomicAdd(&cnt[N1 + u1d[i - nE1]], 1);
        return;
    }

    const int nbase = blockIdx.x * TILE;

    // gather: 64 rows x 32 float4 = 2048 float4, 4 per thread
    #pragma unroll
    for (int r = 0; r < 4; ++r) {
        int f4 = r * 512 + tid;
        int t  = f4 >> 5;
        int c4 = f4 & 31;
        int node = nbase + t;
        if (node < N1) {
            int row = item_ids[node];
            ((float4*)&xs[t][0])[c4] =
                ((const float4*)(item_emb + (size_t)row * EMB))[c4];
        }
    }
    __syncthreads();

    const int cg = tid & 31;
    const int rg = tid >> 5;          // 0..15, owns rows 4rg..4rg+3
    const int j0 = cg * 4;
    const float* W0 = fc_w + j0;
    const float* W3 = fc_w + 3 * EMB * EMB + j0;

    float a0[4][4], a3[4][4];
    #pragma unroll
    for (int r = 0; r < 4; ++r)
        #pragma unroll
        for (int c = 0; c < 4; ++c) { a0[r][c] = 0.f; a3[r][c] = 0.f; }

    // double-buffered weight quads
    float4 wc0[4], wc3[4], wn0[4], wn3[4];
    #pragma unroll
    for (int kk = 0; kk < 4; ++kk) {
        wc0[kk] = *((const float4*)(W0 + (size_t)kk * EMB));
        wc3[kk] = *((const float4*)(W3 + (size_t)kk * EMB));
    }

    for (int k = 0; k < EMB; k += 4) {
        const int kn = k + 4;
        if (kn < EMB) {
            #pragma unroll
            for (int kk = 0; kk < 4; ++kk) {
                wn0[kk] = *((const float4*)(W0 + (size_t)(kn + kk) * EMB));
                wn3[kk] = *((const float4*)(W3 + (size_t)(kn + kk) * EMB));
            }
        }
        #pragma unroll
        for (int r = 0; r < 4; ++r) {
            float4 x = *((const float4*)&xs[rg * 4 + r][k]);
            #pragma unroll
            for (int c = 0; c < 4; ++c) {
                float acc0 = a0[r][c], acc3 = a3[r][c];
                acc0 = fmaf(x.x, F4C(wc0[0], c), acc0);
                acc0 = fmaf(x.y, F4C(wc0[1], c), acc0);
                acc0 = fmaf(x.z, F4C(wc0[2], c), acc0);
                acc0 = fmaf(x.w, F4C(wc0[3], c), acc0);
                acc3 = fmaf(x.x, F4C(wc3[0], c), acc3);
                acc3 = fmaf(x.y, F4C(wc3[1], c), acc3);
                acc3 = fmaf(x.z, F4C(wc3[2], c), acc3);
                acc3 = fmaf(x.w, F4C(wc3[3], c), acc3);
                a0[r][c] = acc0; a3[r][c] = acc3;
            }
        }
        if (kn < EMB) {
            #pragma unroll
            for (int kk = 0; kk < 4; ++kk) { wc0[kk] = wn0[kk]; wc3[kk] = wn3[kk]; }
        }
    }

    // store fs tiles
    #pragma unroll
    for (int r = 0; r < 4; ++r) {
        int row = nbase + rg * 4 + r;
        if (row < N1) {
            float4 v0 = make_float4(a0[r][0], a0[r][1], a0[r][2], a0[r][3]);
            float4 v3 = make_float4(a3[r][0], a3[r][1], a3[r][2], a3[r][3]);
            *((float4*)(fs0 + (size_t)row * EMB + j0)) = v0;
            *((float4*)(fs3 + (size_t)row * EMB + j0)) = v3;
        }
    }

    // fused attention dots: head = j0>>4; 4-lane shfl_xor completes the dot
    float al0v[4], ar0v[4], al3v[4];
    #pragma unroll
    for (int c = 0; c < 4; ++c) {
        al0v[c] = attn_l[j0 + c];
        ar0v[c] = attn_r[j0 + c];
        al3v[c] = attn_l[3 * EMB + j0 + c];
    }
    const int head = j0 >> 4;
    #pragma unroll
    for (int r = 0; r < 4; ++r) {
        float pe = a0[r][0]*al0v[0] + a0[r][1]*al0v[1] + a0[r][2]*al0v[2] + a0[r][3]*al0v[3];
        float pr = a0[r][0]*ar0v[0] + a0[r][1]*ar0v[1] + a0[r][2]*ar0v[2] + a0[r][3]*ar0v[3];
        float p3 = a3[r][0]*al3v[0] + a3[r][1]*al3v[1] + a3[r][2]*al3v[2] + a3[r][3]*al3v[3];
        pe += __shfl_xor(pe, 1); pe += __shfl_xor(pe, 2);
        pr += __shfl_xor(pr, 1); pr += __shfl_xor(pr, 2);
        p3 += __shfl_xor(p3, 1); p3 += __shfl_xor(p3, 2);
        int row = nbase + rg * 4 + r;
        if ((cg & 3) == 0 && row < N1) {
            el0[(size_t)row * NH + head] = pe;
            er0[(size_t)row * NH + head] = pr;
            el3[(size_t)row * NH + head] = p3;
        }
    }
}

// ---------------------------------------------------------------------------
// CSR build: exclusive scan + cursor scatter (count fused into k_featcnt)
// ---------------------------------------------------------------------------
__global__ __launch_bounds__(256) void k_scan_partial(
    const int* __restrict__ cnt, int n, int* __restrict__ part)
{
    __shared__ int sh[256];
    int base = blockIdx.x * 1024 + threadIdx.x * 4;
    int s = 0;
    #pragma unroll
    for (int k = 0; k < 4; ++k) { int i = base + k; if (i < n) s += cnt[i]; }
    sh[threadIdx.x] = s;
    __syncthreads();
    for (int off = 128; off > 0; off >>= 1) {
        if (threadIdx.x < off) sh[threadIdx.x] += sh[threadIdx.x + off];
        __syncthreads();
    }
    if (threadIdx.x == 0) part[blockIdx.x] = sh[0];
}

__global__ __launch_bounds__(256) void k_scan_mid(int* part, int np)
{
    __shared__ int sh[256];
    int tid = threadIdx.x;
    int v = (tid < np) ? part[tid] : 0;
    sh[tid] = v;
    __syncthreads();
    for (int off = 1; off < 256; off <<= 1) {
        int t = (tid >= off) ? sh[tid - off] : 0;
        __syncthreads();
        sh[tid] += t;
        __syncthreads();
    }
    if (tid < np) part[tid] = sh[tid] - v;   // exclusive
}

__global__ __launch_bounds__(256) void k_scan_final(
    const int* __restrict__ cnt, const int* __restrict__ part, int n, int nE,
    int* __restrict__ off, int* __restrict__ cur)
{
    __shared__ int sh[256];
    int tid = threadIdx.x;
    int base = blockIdx.x * 1024 + tid * 4;
    int c[4]; int s = 0;
    #pragma unroll
    for (int k = 0; k < 4; ++k) { int i = base + k; c[k] = (i < n) ? cnt[i] : 0; s += c[k]; }
    sh[tid] = s;
    __syncthreads();
    int own = s;
    for (int offv = 1; offv < 256; offv <<= 1) {
        int t = (tid >= offv) ? sh[tid - offv] : 0;
        __syncthreads();
        sh[tid] += t;
        __syncthreads();
    }
    int excl = sh[tid] - own + part[blockIdx.x];
    #pragma unroll
    for (int k = 0; k < 4; ++k) {
        int i = base + k;
        if (i < n) { off[i] = excl; cur[i] = excl; excl += c[k]; }
    }
    if (blockIdx.x == 0 && tid == 0) off[n] = nE;
}

__global__ __launch_bounds__(256) void k_scatter2(
    const int* __restrict__ s1s, const int* __restrict__ s1d, int nE1,
    const int* __restrict__ u1s, const int* __restrict__ u1d, int nE3,
    int* __restrict__ cur, int* __restrict__ esrc)
{
    int i = blockIdx.x * 256 + threadIdx.x;
    if (i < nE1) {
        int pos = atomicAdd(&cur[s1d[i]], 1);
        esrc[pos] = s1s[i];
    } else if (i < nE1 + nE3) {
        int j = i - nE1;
        int pos = atomicAdd(&cur[N1 + u1d[j]], 1);
        esrc[pos] = u1s[j];
    }
}

// ---------------------------------------------------------------------------
// k_agg: merged pull aggregation over combined CSR. One wave per dst, lane
// owns 2 cols. Inner edge loop unrolled x4 (4 independent gathers in flight).
// ---------------------------------------------------------------------------
__global__ __launch_bounds__(256) void k_agg(
    const int* __restrict__ off, const int* __restrict__ esrc,
    const float* __restrict__ el0, const float* __restrict__ er0,
    const float* __restrict__ fs0,
    const float* __restrict__ el3, const float* __restrict__ fs3,
    const float* __restrict__ item_emb, const int* __restrict__ item_ids,
    const float* __restrict__ conv_b,
    float* __restrict__ val1, float* __restrict__ val2)
{
    const int wid  = blockIdx.x * 4 + (threadIdx.x >> 6);
    const int lane = threadIdx.x & 63;
    const int h = lane >> 3;
    const int c = lane * 2;

    const float* el; const float* fs;
    float erh, b0, b1;
    bool g1 = (wid < N1);
    if (g1) {
        el = el0; fs = fs0;
        erh = er0[(size_t)wid * NH + h];
        b0 = conv_b[0 * EMB + c]     + conv_b[4 * EMB + c];
        b1 = conv_b[0 * EMB + c + 1] + conv_b[4 * EMB + c + 1];
    } else {
        el = el3; fs = fs3;
        erh = 0.f;
        b0 = conv_b[3 * EMB + c]     + conv_b[1 * EMB + c]     + conv_b[6 * EMB + c];
        b1 = conv_b[3 * EMB + c + 1] + conv_b[1 * EMB + c + 1] + conv_b[6 * EMB + c + 1];
    }

    const int beg = off[wid], end = off[wid + 1];
    float ax = 0.f, ay = 0.f, wsum = 0.f;
    for (int base = beg; base < end; base += 64) {
        int myS = (base + lane < end) ? esrc[base + lane] : 0;  // coalesced
        int cnt = min(64, end - base);
        int i = 0;
        for (; i + 3 < cnt; i += 4) {
            int sA = __shfl(myS, i);
            int sB = __shfl(myS, i + 1);
            int sC = __shfl(myS, i + 2);
            int sD = __shfl(myS, i + 3);
            float eA = el[(size_t)sA * NH + h] + erh;
            float eB = el[(size_t)sB * NH + h] + erh;
            float eC = el[(size_t)sC * NH + h] + erh;
            float eD = el[(size_t)sD * NH + h] + erh;
            float2 fA = ((const float2*)(fs + (size_t)sA * EMB))[lane];
            float2 fB = ((const float2*)(fs + (size_t)sB * EMB))[lane];
            float2 fC = ((const float2*)(fs + (size_t)sC * EMB))[lane];
            float2 fD = ((const float2*)(fs + (size_t)sD * EMB))[lane];
            eA = (eA > 0.f) ? eA : NEG * eA;
            eB = (eB > 0.f) ? eB : NEG * eB;
            eC = (eC > 0.f) ? eC : NEG * eC;
            eD = (eD > 0.f) ? eD : NEG * eD;
            float wA = __expf(eA), wB = __expf(eB);
            float wC = __expf(eC), wD = __expf(eD);
            ax = fmaf(wA, fA.x, fmaf(wB, fB.x, fmaf(wC, fC.x, fmaf(wD, fD.x, ax))));
            ay = fmaf(wA, fA.y, fmaf(wB, fB.y, fmaf(wC, fC.y, fmaf(wD, fD.y, ay))));
            wsum += (wA + wB) + (wC + wD);
        }
        for (; i < cnt; ++i) {
            int s = __shfl(myS, i);
            float e = el[(size_t)s * NH + h] + erh;
            e = (e > 0.f) ? e : NEG * e;
            float w = __expf(e);
            float2 f2 = ((const float2*)(fs + (size_t)s * EMB))[lane];
            ax = fmaf(w, f2.x, ax);
            ay = fmaf(w, f2.y, ay);
            wsum += w;
        }
    }

    float vx = 0.f, vy = 0.f;
    if (end > beg) { float inv = 1.f / wsum; vx = ax * inv; vy = ay * inv; }
    if (g1) {
        float2 r = ((const float2*)(item_emb + (size_t)item_ids[wid] * EMB))[lane];
        vx += r.x; vy += r.y;
    }
    float2 o; o.x = vx + b0; o.y = vy + b1;
    float* out = g1 ? (val1 + (size_t)wid * EMB) : (val2 + (size_t)(wid - N1) * EMB);
    ((float2*)out)[lane] = o;
}

// ---------------------------------------------------------------------------
// k_mlp: hidden layer y = relu(val@W1 + b1), column sums into mean[].
// 512 threads, 64-row tile, 4x4 register tiling, double-buffered weights.
// Single launch: blocks [0,MLPB1) -> val1/mean1, [MLPB1,MLPB1+MLPB2) -> val2.
// ---------------------------------------------------------------------------
__global__ __launch_bounds__(512) void k_mlp(
    const float* __restrict__ val1, const float* __restrict__ val2,
    const float* __restrict__ r_w1, const float* __restrict__ r_b1,
    float* __restrict__ mean1, float* __restrict__ mean2)
{
    __shared__ float xs[TILE][LPAD];   // 33.8 KB
    __shared__ float red[16][EMB];     // 8 KB

    const int tid = threadIdx.x;
    const int b = blockIdx.x;
    const bool g1 = (b < MLPB1);
    const float* val  = g1 ? val1 : val2;
    const float* rw1  = g1 ? r_w1 : r_w1 + EMB * EMB;
    const float* rb1  = g1 ? r_b1 : r_b1 + EMB;
    float*       mean = g1 ? mean1 : mean2;
    const int nrows = g1 ? N1 : N2;
    const int nbase = (g1 ? b : b - MLPB1) * TILE;

    #pragma unroll
    for (int r = 0; r < 4; ++r) {
        int f4 = r * 512 + tid;
        int t  = f4 >> 5;
        int c4 = f4 & 31;
        int row = nbase + t;
        if (row < nrows)
            ((float4*)&xs[t][0])[c4] =
                ((const float4*)(val + (size_t)row * EMB))[c4];
    }
    __syncthreads();

    const int cg = tid & 31;
    const int rg = tid >> 5;          // 0..15
    const int j0 = cg * 4;
    const float* W = rw1 + j0;

    float a[4][4];
    #pragma unroll
    for (int r = 0; r < 4; ++r)
        #pragma unroll
        for (int c = 0; c < 4; ++c) a[r][c] = 0.f;

    float4 wc[4], wn[4];
    #pragma unroll
    for (int kk = 0; kk < 4; ++kk) wc[kk] = *((const float4*)(W + (size_t)kk * EMB));

    for (int k = 0; k < EMB; k += 4) {
        const int kn = k + 4;
        if (kn < EMB) {
            #pragma unroll
            for (int kk = 0; kk < 4; ++kk)
                wn[kk] = *((const float4*)(W + (size_t)(kn + kk) * EMB));
        }
        #pragma unroll
        for (int r = 0; r < 4; ++r) {
            float4 x = *((const float4*)&xs[rg * 4 + r][k]);
            #pragma unroll
            for (int c = 0; c < 4; ++c) {
                float acc = a[r][c];
                acc = fmaf(x.x, F4C(wc[0], c), acc);
                acc = fmaf(x.y, F4C(wc[1], c), acc);
                acc = fmaf(x.z, F4C(wc[2], c), acc);
                acc = fmaf(x.w, F4C(wc[3], c), acc);
                a[r][c] = acc;
            }
        }
        if (kn < EMB) {
            #pragma unroll
            for (int kk = 0; kk < 4; ++kk) wc[kk] = wn[kk];
        }
    }

    float b1v[4];
    #pragma unroll
    for (int c = 0; c < 4; ++c) b1v[c] = rb1[j0 + c];
    float cs[4] = {0.f, 0.f, 0.f, 0.f};
    #pragma unroll
    for (int r = 0; r < 4; ++r) {
        int row = nbase + rg * 4 + r;
        if (row < nrows) {
            #pragma unroll
            for (int c = 0; c < 4; ++c)
                cs[c] += fmaxf(a[r][c] + b1v[c], 0.f);
        }
    }
    *((float4*)&red[rg][j0]) = make_float4(cs[0], cs[1], cs[2], cs[3]);
    __syncthreads();
    if (tid < EMB) {
        float s = 0.f;
        #pragma unroll
        for (int g = 0; g < 16; ++g) s += red[g][tid];
        atomicAdd(mean + tid, s);
    }
}

// ---------------------------------------------------------------------------
// k_final: second MLP layers on the column means + constant gran3 row +
// softmax(gran_w) + fused output.
// ---------------------------------------------------------------------------
__global__ __launch_bounds__(128) void k_final(
    const float* __restrict__ mean1, const float* __restrict__ mean2,
    const float* __restrict__ conv_b,
    const float* __restrict__ r_w1, const float* __restrict__ r_b1,
    const float* __restrict__ r_w2, const float* __restrict__ r_b2,
    const float* __restrict__ gran_w, float* __restrict__ out)
{
    __shared__ float m1[EMB], m2[EMB], x3[EMB], t3[EMB];
    const int j = threadIdx.x;
    m1[j] = mean1[j] * (1.f / N1);
    m2[j] = mean2[j] * (1.f / N2);
    x3[j] = conv_b[2 * EMB + j] + conv_b[5 * EMB + j];
    __syncthreads();

    float a = r_b1[2 * EMB + j];
    for (int k = 0; k < EMB; ++k)
        a = fmaf(x3[k], r_w1[2 * EMB * EMB + k * EMB + j], a);
    t3[j] = fmaxf(a, 0.f);
    __syncthreads();

    float r1 = r_b2[0 * EMB + j];
    float r2 = r_b2[1 * EMB + j];
    float r3 = r_b2[2 * EMB + j];
    for (int k = 0; k < EMB; ++k) {
        r1 = fmaf(m1[k], r_w2[0 * EMB * EMB + k * EMB + j], r1);
        r2 = fmaf(m2[k], r_w2[1 * EMB * EMB + k * EMB + j], r2);
        r3 = fmaf(t3[k], r_w2[2 * EMB * EMB + k * EMB + j], r3);
    }

    float g0 = gran_w[0], g1 = gran_w[1], g2 = gran_w[2];
    float mx = fmaxf(g0, fmaxf(g1, g2));
    float e0 = expf(g0 - mx), e1 = expf(g1 - mx), e2 = expf(g2 - mx);
    float s = e0 + e1 + e2;
    float w0 = e0 / s, w1 = e1 / s, w2 = e2 / s;

    out[j]       = w0 * r1 + w1 * r2 + w2 * r3;
    out[128 + j] = r1;
    out[256 + j] = r2;
    out[384 + j] = r3;
    if (j < 3) out[512 + j] = (j == 0) ? w0 : (j == 1) ? w1 : w2;
}

extern "C" void kernel_launch(void* const* d_in, const int* in_sizes, int n_in,
                              void* d_out, int out_size, void* d_ws, size_t ws_size,
                              hipStream_t stream) {
    const int*   item_ids = (const int*)d_in[0];
    const int*   s1s = (const int*)d_in[1];
    const int*   s1d = (const int*)d_in[2];
    const int*   u1s = (const int*)d_in[7];
    const int*   u1d = (const int*)d_in[8];
    const float* item_emb = (const float*)d_in[15];
    const float* fc_w   = (const float*)d_in[16];
    const float* attn_l = (const float*)d_in[17];
    const float* attn_r = (const float*)d_in[18];
    const float* conv_b = (const float*)d_in[19];
    const float* r_w1 = (const float*)d_in[20];
    const float* r_b1 = (const float*)d_in[21];
    const float* r_w2 = (const float*)d_in[22];
    const float* r_b2 = (const float*)d_in[23];
    const float* gran_w = (const float*)d_in[24];

    const int nE1 = in_sizes[1];   // 600000
    const int nE3 = in_sizes[7];   // 200000
    const int nEt = nE1 + nE3;
    const int ND  = N1 + N2;       // combined dst domain

    float* ws = (float*)d_ws;
    // --- zero region (one memset): mean1 | mean2 | cnt (combined)
    float* mean1 = ws;
    float* mean2 = mean1 + EMB;
    int*   cnt   = (int*)(mean2 + EMB);      // ND
    size_t zeroN = 2 * EMB + ND;
    // --- non-zeroed scratch (keep 16B alignment for the float4 arrays)
    int*   off   = cnt + ND;                 // ND+1 (padded to ND+4)
    int*   cur   = off + ND + 4;             // ND
    int*   part  = cur + ND;                 // 128 (need 118)
    int*   esrc  = part + 128;               // nEt (800000, %4==0)
    float* fs0   = (float*)(esrc + nEt);     // N1*128
    float* fs3   = fs0 + (size_t)N1 * EMB;   // N1*128
    float* el0   = fs3 + (size_t)N1 * EMB;   // N1*8
    float* er0   = el0 + (size_t)N1 * NH;    // N1*8
    float* el3   = er0 + (size_t)N1 * NH;    // N1*8
    float* val1  = el3 + (size_t)N1 * NH;    // N1*128
    float* val2  = val1 + (size_t)N1 * EMB;  // N2*128

    hipMemsetAsync(ws, 0, zeroN * sizeof(float), stream);

    // features + attention dots + CSR degree count (fused, independent blocks)
    const int cntBlks = (nEt + 511) / 512;   // 1563
    k_featcnt<<<FEAT_BLKS + cntBlks, 512, 0, stream>>>(
        item_emb, item_ids, fc_w, attn_l, attn_r, fs0, fs3, el0, er0, el3,
        s1d, nE1, u1d, nE3, cnt);

    // CSR scan + scatter over combined dst domain
    const int nch = (ND + 1023) / 1024;      // 118
    k_scan_partial<<<nch, 256, 0, stream>>>(cnt, ND, part);
    k_scan_mid<<<1, 256, 0, stream>>>(part, nch);
    k_scan_final<<<nch, 256, 0, stream>>>(cnt, part, ND, nEt, off, cur);
    k_scatter2<<<(nEt + 255) / 256, 256, 0, stream>>>(s1s, s1d, nE1,
                                                      u1s, u1d, nE3, cur, esrc);

    // merged pull aggregation (writes fully assembled rows)
    k_agg<<<ND / 4, 256, 0, stream>>>(off, esrc, el0, er0, fs0, el3, fs3,
                                      item_emb, item_ids, conv_b, val1, val2);

    // hidden MLP + column-sum reduction (both granularities, one launch)
    k_mlp<<<MLPB1 + MLPB2, 512, 0, stream>>>(val1, val2, r_w1, r_b1, mean1, mean2);

    k_final<<<1, 128, 0, stream>>>(mean1, mean2, conv_b, r_w1, r_b1, r_w2, r_b2,
                                   gran_w, (float*)d_out);
}

// Round 12
// 552.047 us; speedup vs baseline: 4.8375x; 4.8375x over previous
//
#include <hip/hip_runtime.h>
#include <math.h>

#define N1 100000
#define N2 20000
#define EMB 128
#define NH 8
#define TILE 64
#define LPAD 132   // LDS row pitch (floats): 132 ≡ 4 (mod 32) banks, 16B-aligned

static constexpr float NEG = 0.2f;

// compile-time float4 component select (c must be a constant after unroll)
#define F4C(v, c) ((c) == 0 ? (v).x : (c) == 1 ? (v).y : (c) == 2 ? (v).z : (v).w)

// ---------------------------------------------------------------------------
// k_feat64: gather item_emb[item_ids] into LDS (64-row tile), dual GEMM
// fs0 = h@W0, fs3 = h@W3. Weights staged through LDS in 16-row K-chunks
// (contiguous 8KB per matrix, fully coalesced): inner loop is pure LDS+FMA,
// no per-quad global waits, no weight registers (no spill risk).
// 256 threads: cg = tid&31 owns cols 4cg..+3, rg = tid>>5 owns rows 8rg..+7.
// Fused attention-dot epilogue (el0/er0/el3) via 4-lane shfl reduction.
// ---------------------------------------------------------------------------
__global__ __launch_bounds__(256) void k_feat64(
    const float* __restrict__ item_emb, const int* __restrict__ item_ids,
    const float* __restrict__ fc_w, const float* __restrict__ attn_l,
    const float* __restrict__ attn_r,
    float* __restrict__ fs0, float* __restrict__ fs3,
    float* __restrict__ el0, float* __restrict__ er0, float* __restrict__ el3)
{
    __shared__ float xs[TILE][LPAD];      // 33.8 KB
    __shared__ float wb0[16 * EMB];       // 8 KB  (W0 K-chunk)
    __shared__ float wb3[16 * EMB];       // 8 KB  (W3 K-chunk)

    const int tid = threadIdx.x;
    const int nbase = blockIdx.x * TILE;

    // gather: 64 rows x 32 float4 = 2048 float4, 8 per thread
    #pragma unroll
    for (int r = 0; r < 8; ++r) {
        int f4 = r * 256 + tid;
        int t  = f4 >> 5;
        int c4 = f4 & 31;
        int node = nbase + t;
        if (node < N1) {
            int row = item_ids[node];
            ((float4*)&xs[t][0])[c4] =
                ((const float4*)(item_emb + (size_t)row * EMB))[c4];
        }
    }

    const int cg = tid & 31;
    const int rg = tid >> 5;
    const int j0 = cg * 4;

    float a0[8][4], a3[8][4];
    #pragma unroll
    for (int r = 0; r < 8; ++r)
        #pragma unroll
        for (int c = 0; c < 4; ++c) { a0[r][c] = 0.f; a3[r][c] = 0.f; }

    for (int chunk = 0; chunk < EMB / 16; ++chunk) {
        const int kbase = chunk * 16;
        // stage 16 contiguous weight rows of each matrix (8 KB each, coalesced)
        __syncthreads();   // all waves done reading previous chunk
        {
            const float4* src0 = (const float4*)(fc_w + (size_t)kbase * EMB);
            const float4* src3 = (const float4*)(fc_w + 3 * EMB * EMB + (size_t)kbase * EMB);
            ((float4*)wb0)[tid]       = src0[tid];
            ((float4*)wb0)[tid + 256] = src0[tid + 256];
            ((float4*)wb3)[tid]       = src3[tid];
            ((float4*)wb3)[tid + 256] = src3[tid + 256];
        }
        __syncthreads();

        #pragma unroll
        for (int q = 0; q < 4; ++q) {
            float4 wc0[4], wc3[4];
            #pragma unroll
            for (int kk = 0; kk < 4; ++kk) {
                wc0[kk] = *((const float4*)&wb0[(q * 4 + kk) * EMB + j0]);
                wc3[kk] = *((const float4*)&wb3[(q * 4 + kk) * EMB + j0]);
            }
            #pragma unroll
            for (int r = 0; r < 8; ++r) {
                float4 x = *((const float4*)&xs[rg * 8 + r][kbase + q * 4]);
                #pragma unroll
                for (int c = 0; c < 4; ++c) {
                    float acc0 = a0[r][c], acc3 = a3[r][c];
                    acc0 = fmaf(x.x, F4C(wc0[0], c), acc0);
                    acc0 = fmaf(x.y, F4C(wc0[1], c), acc0);
                    acc0 = fmaf(x.z, F4C(wc0[2], c), acc0);
                    acc0 = fmaf(x.w, F4C(wc0[3], c), acc0);
                    acc3 = fmaf(x.x, F4C(wc3[0], c), acc3);
                    acc3 = fmaf(x.y, F4C(wc3[1], c), acc3);
                    acc3 = fmaf(x.z, F4C(wc3[2], c), acc3);
                    acc3 = fmaf(x.w, F4C(wc3[3], c), acc3);
                    a0[r][c] = acc0; a3[r][c] = acc3;
                }
            }
        }
    }

    // store fs tiles
    #pragma unroll
    for (int r = 0; r < 8; ++r) {
        int row = nbase + rg * 8 + r;
        if (row < N1) {
            float4 v0 = make_float4(a0[r][0], a0[r][1], a0[r][2], a0[r][3]);
            float4 v3 = make_float4(a3[r][0], a3[r][1], a3[r][2], a3[r][3]);
            *((float4*)(fs0 + (size_t)row * EMB + j0)) = v0;
            *((float4*)(fs3 + (size_t)row * EMB + j0)) = v3;
        }
    }

    // fused attention dots: head = j0>>4; 4-lane shfl_xor completes the dot
    float al0v[4], ar0v[4], al3v[4];
    #pragma unroll
    for (int c = 0; c < 4; ++c) {
        al0v[c] = attn_l[j0 + c];
        ar0v[c] = attn_r[j0 + c];
        al3v[c] = attn_l[3 * EMB + j0 + c];
    }
    const int head = j0 >> 4;
    #pragma unroll
    for (int r = 0; r < 8; ++r) {
        float pe = a0[r][0]*al0v[0] + a0[r][1]*al0v[1] + a0[r][2]*al0v[2] + a0[r][3]*al0v[3];
        float pr = a0[r][0]*ar0v[0] + a0[r][1]*ar0v[1] + a0[r][2]*ar0v[2] + a0[r][3]*ar0v[3];
        float p3 = a3[r][0]*al3v[0] + a3[r][1]*al3v[1] + a3[r][2]*al3v[2] + a3[r][3]*al3v[3];
        pe += __shfl_xor(pe, 1); pe += __shfl_xor(pe, 2);
        pr += __shfl_xor(pr, 1); pr += __shfl_xor(pr, 2);
        p3 += __shfl_xor(p3, 1); p3 += __shfl_xor(p3, 2);
        int row = nbase + rg * 8 + r;
        if ((cg & 3) == 0 && row < N1) {
            el0[(size_t)row * NH + head] = pe;
            er0[(size_t)row * NH + head] = pr;
            el3[(size_t)row * NH + head] = p3;
        }
    }
}

// ---------------------------------------------------------------------------
// merged CSR build over combined dst domain [0,N1) ∪ [N1,N1+N2)
// ---------------------------------------------------------------------------
__global__ __launch_bounds__(256) void k_count2(
    const int* __restrict__ s1d, int nE1,
    const int* __restrict__ u1d, int nE3, int* __restrict__ cnt)
{
    int i = blockIdx.x * 256 + threadIdx.x;
    if (i < nE1) atomicAdd(&cnt[s1d[i]], 1);
    else if (i < nE1 + nE3) atomicAdd(&cnt[N1 + u1d[i - nE1]], 1);
}

__global__ __launch_bounds__(256) void k_scan_partial(
    const int* __restrict__ cnt, int n, int* __restrict__ part)
{
    __shared__ int sh[256];
    int base = blockIdx.x * 1024 + threadIdx.x * 4;
    int s = 0;
    #pragma unroll
    for (int k = 0; k < 4; ++k) { int i = base + k; if (i < n) s += cnt[i]; }
    sh[threadIdx.x] = s;
    __syncthreads();
    for (int off = 128; off > 0; off >>= 1) {
        if (threadIdx.x < off) sh[threadIdx.x] += sh[threadIdx.x + off];
        __syncthreads();
    }
    if (threadIdx.x == 0) part[blockIdx.x] = sh[0];
}

__global__ __launch_bounds__(256) void k_scan_mid(int* part, int np)
{
    __shared__ int sh[256];
    int tid = threadIdx.x;
    int v = (tid < np) ? part[tid] : 0;
    sh[tid] = v;
    __syncthreads();
    for (int off = 1; off < 256; off <<= 1) {
        int t = (tid >= off) ? sh[tid - off] : 0;
        __syncthreads();
        sh[tid] += t;
        __syncthreads();
    }
    if (tid < np) part[tid] = sh[tid] - v;   // exclusive
}

__global__ __launch_bounds__(256) void k_scan_final(
    const int* __restrict__ cnt, const int* __restrict__ part, int n, int nE,
    int* __restrict__ off, int* __restrict__ cur)
{
    __shared__ int sh[256];
    int tid = threadIdx.x;
    int base = blockIdx.x * 1024 + tid * 4;
    int c[4]; int s = 0;
    #pragma unroll
    for (int k = 0; k < 4; ++k) { int i = base + k; c[k] = (i < n) ? cnt[i] : 0; s += c[k]; }
    sh[tid] = s;
    __syncthreads();
    int own = s;
    for (int offv = 1; offv < 256; offv <<= 1) {
        int t = (tid >= offv) ? sh[tid - offv] : 0;
        __syncthreads();
        sh[tid] += t;
        __syncthreads();
    }
    int excl = sh[tid] - own + part[blockIdx.x];
    #pragma unroll
    for (int k = 0; k < 4; ++k) {
        int i = base + k;
        if (i < n) { off[i] = excl; cur[i] = excl; excl += c[k]; }
    }
    if (blockIdx.x == 0 && tid == 0) off[n] = nE;
}

__global__ __launch_bounds__(256) void k_scatter2(
    const int* __restrict__ s1s, const int* __restrict__ s1d, int nE1,
    const int* __restrict__ u1s, const int* __restrict__ u1d, int nE3,
    int* __restrict__ cur, int* __restrict__ esrc)
{
    int i = blockIdx.x * 256 + threadIdx.x;
    if (i < nE1) {
        int pos = atomicAdd(&cur[s1d[i]], 1);
        esrc[pos] = s1s[i];
    } else if (i < nE1 + nE3) {
        int j = i - nE1;
        int pos = atomicAdd(&cur[N1 + u1d[j]], 1);
        esrc[pos] = u1s[j];
    }
}

// ---------------------------------------------------------------------------
// k_agg: merged pull aggregation over combined CSR. One wave per dst, lane
// owns 2 cols. Inner loop unrolled x2, __expf. Zero float atomics.
// ---------------------------------------------------------------------------
__global__ __launch_bounds__(256) void k_agg(
    const int* __restrict__ off, const int* __restrict__ esrc,
    const float* __restrict__ el0, const float* __restrict__ er0,
    const float* __restrict__ fs0,
    const float* __restrict__ el3, const float* __restrict__ fs3,
    const float* __restrict__ item_emb, const int* __restrict__ item_ids,
    const float* __restrict__ conv_b,
    float* __restrict__ val1, float* __restrict__ val2)
{
    const int wid  = blockIdx.x * 4 + (threadIdx.x >> 6);
    const int lane = threadIdx.x & 63;
    const int h = lane >> 3;
    const int c = lane * 2;

    const float* el; const float* fs;
    float erh, b0, b1;
    bool g1 = (wid < N1);
    if (g1) {
        el = el0; fs = fs0;
        erh = er0[(size_t)wid * NH + h];
        b0 = conv_b[0 * EMB + c]     + conv_b[4 * EMB + c];
        b1 = conv_b[0 * EMB + c + 1] + conv_b[4 * EMB + c + 1];
    } else {
        el = el3; fs = fs3;
        erh = 0.f;
        b0 = conv_b[3 * EMB + c]     + conv_b[1 * EMB + c]     + conv_b[6 * EMB + c];
        b1 = conv_b[3 * EMB + c + 1] + conv_b[1 * EMB + c + 1] + conv_b[6 * EMB + c + 1];
    }

    const int beg = off[wid], end = off[wid + 1];
    float ax = 0.f, ay = 0.f, wsum = 0.f;
    for (int base = beg; base < end; base += 64) {
        int myS = (base + lane < end) ? esrc[base + lane] : 0;  // coalesced
        int cnt = min(64, end - base);
        int i = 0;
        for (; i + 1 < cnt; i += 2) {
            int sA = __shfl(myS, i);
            int sB = __shfl(myS, i + 1);
            float eA = el[(size_t)sA * NH + h] + erh;
            float eB = el[(size_t)sB * NH + h] + erh;
            eA = (eA > 0.f) ? eA : NEG * eA;
            eB = (eB > 0.f) ? eB : NEG * eB;
            float wA = __expf(eA);
            float wB = __expf(eB);
            float2 fA = ((const float2*)(fs + (size_t)sA * EMB))[lane];
            float2 fB = ((const float2*)(fs + (size_t)sB * EMB))[lane];
            ax = fmaf(wA, fA.x, fmaf(wB, fB.x, ax));
            ay = fmaf(wA, fA.y, fmaf(wB, fB.y, ay));
            wsum += wA + wB;
        }
        if (i < cnt) {
            int s = __shfl(myS, i);
            float e = el[(size_t)s * NH + h] + erh;
            e = (e > 0.f) ? e : NEG * e;
            float w = __expf(e);
            float2 f2 = ((const float2*)(fs + (size_t)s * EMB))[lane];
            ax = fmaf(w, f2.x, ax);
            ay = fmaf(w, f2.y, ay);
            wsum += w;
        }
    }

    float vx = 0.f, vy = 0.f;
    if (end > beg) { float inv = 1.f / wsum; vx = ax * inv; vy = ay * inv; }
    if (g1) {
        float2 r = ((const float2*)(item_emb + (size_t)item_ids[wid] * EMB))[lane];
        vx += r.x; vy += r.y;
    }
    float2 o; o.x = vx + b0; o.y = vy + b1;
    float* out = g1 ? (val1 + (size_t)wid * EMB) : (val2 + (size_t)(wid - N1) * EMB);
    ((float2*)out)[lane] = o;
}

// ---------------------------------------------------------------------------
// k_mlp64: hidden layer y = relu(val@W1 + b1), column sums into mean[].
// 64-row tile, 8x4 register tiling, double-buffered weight loads. 256 thr.
// ---------------------------------------------------------------------------
__global__ __launch_bounds__(256) void k_mlp64(
    const float* __restrict__ val, int nrows,
    const float* __restrict__ rw1, const float* __restrict__ rb1,
    float* __restrict__ mean)
{
    __shared__ float xs[TILE][LPAD];   // 33 KB
    __shared__ float red[8][EMB];      // 4 KB

    const int tid = threadIdx.x;
    const int nbase = blockIdx.x * TILE;

    #pragma unroll
    for (int r = 0; r < 8; ++r) {
        int f4 = r * 256 + tid;
        int t  = f4 >> 5;
        int c4 = f4 & 31;
        int row = nbase + t;
        if (row < nrows)
            ((float4*)&xs[t][0])[c4] =
                ((const float4*)(val + (size_t)row * EMB))[c4];
    }
    __syncthreads();

    const int cg = tid & 31;
    const int rg = tid >> 5;
    const int j0 = cg * 4;
    const float* W = rw1 + j0;

    float a[8][4];
    #pragma unroll
    for (int r = 0; r < 8; ++r)
        #pragma unroll
        for (int c = 0; c < 4; ++c) a[r][c] = 0.f;

    float4 wc[4], wn[4];
    #pragma unroll
    for (int kk = 0; kk < 4; ++kk) wc[kk] = *((const float4*)(W + (size_t)kk * EMB));

    for (int k = 0; k < EMB; k += 4) {
        const int kn = k + 4;
        if (kn < EMB) {
            #pragma unroll
            for (int kk = 0; kk < 4; ++kk)
                wn[kk] = *((const float4*)(W + (size_t)(kn + kk) * EMB));
        }
        #pragma unroll
        for (int r = 0; r < 8; ++r) {
            float4 x = *((const float4*)&xs[rg * 8 + r][k]);
            #pragma unroll
            for (int c = 0; c < 4; ++c) {
                float acc = a[r][c];
                acc = fmaf(x.x, F4C(wc[0], c), acc);
                acc = fmaf(x.y, F4C(wc[1], c), acc);
                acc = fmaf(x.z, F4C(wc[2], c), acc);
                acc = fmaf(x.w, F4C(wc[3], c), acc);
                a[r][c] = acc;
            }
        }
        if (kn < EMB) {
            #pragma unroll
            for (int kk = 0; kk < 4; ++kk) wc[kk] = wn[kk];
        }
    }

    float b1v[4];
    #pragma unroll
    for (int c = 0; c < 4; ++c) b1v[c] = rb1[j0 + c];
    float cs[4] = {0.f, 0.f, 0.f, 0.f};
    #pragma unroll
    for (int r = 0; r < 8; ++r) {
        int row = nbase + rg * 8 + r;
        if (row < nrows) {
            #pragma unroll
            for (int c = 0; c < 4; ++c)
                cs[c] += fmaxf(a[r][c] + b1v[c], 0.f);
        }
    }
    *((float4*)&red[rg][j0]) = make_float4(cs[0], cs[1], cs[2], cs[3]);
    __syncthreads();
    if (tid < EMB) {
        float s = 0.f;
        #pragma unroll
        for (int g = 0; g < 8; ++g) s += red[g][tid];
        atomicAdd(mean + tid, s);
    }
}

// ---------------------------------------------------------------------------
// k_final: second MLP layers on the column means + constant gran3 row +
// softmax(gran_w) + fused output.
// ---------------------------------------------------------------------------
__global__ __launch_bounds__(128) void k_final(
    const float* __restrict__ mean1, const float* __restrict__ mean2,
    const float* __restrict__ conv_b,
    const float* __restrict__ r_w1, const float* __restrict__ r_b1,
    const float* __restrict__ r_w2, const float* __restrict__ r_b2,
    const float* __restrict__ gran_w, float* __restrict__ out)
{
    __shared__ float m1[EMB], m2[EMB], x3[EMB], t3[EMB];
    const int j = threadIdx.x;
    m1[j] = mean1[j] * (1.f / N1);
    m2[j] = mean2[j] * (1.f / N2);
    x3[j] = conv_b[2 * EMB + j] + conv_b[5 * EMB + j];
    __syncthreads();

    float a = r_b1[2 * EMB + j];
    for (int k = 0; k < EMB; ++k)
        a = fmaf(x3[k], r_w1[2 * EMB * EMB + k * EMB + j], a);
    t3[j] = fmaxf(a, 0.f);
    __syncthreads();

    float r1 = r_b2[0 * EMB + j];
    float r2 = r_b2[1 * EMB + j];
    float r3 = r_b2[2 * EMB + j];
    for (int k = 0; k < EMB; ++k) {
        r1 = fmaf(m1[k], r_w2[0 * EMB * EMB + k * EMB + j], r1);
        r2 = fmaf(m2[k], r_w2[1 * EMB * EMB + k * EMB + j], r2);
        r3 = fmaf(t3[k], r_w2[2 * EMB * EMB + k * EMB + j], r3);
    }

    float g0 = gran_w[0], g1 = gran_w[1], g2 = gran_w[2];
    float mx = fmaxf(g0, fmaxf(g1, g2));
    float e0 = expf(g0 - mx), e1 = expf(g1 - mx), e2 = expf(g2 - mx);
    float s = e0 + e1 + e2;
    float w0 = e0 / s, w1 = e1 / s, w2 = e2 / s;

    out[j]       = w0 * r1 + w1 * r2 + w2 * r3;
    out[128 + j] = r1;
    out[256 + j] = r2;
    out[384 + j] = r3;
    if (j < 3) out[512 + j] = (j == 0) ? w0 : (j == 1) ? w1 : w2;
}

extern "C" void kernel_launch(void* const* d_in, const int* in_sizes, int n_in,
                              void* d_out, int out_size, void* d_ws, size_t ws_size,
                              hipStream_t stream) {
    const int*   item_ids = (const int*)d_in[0];
    const int*   s1s = (const int*)d_in[1];
    const int*   s1d = (const int*)d_in[2];
    const int*   u1s = (const int*)d_in[7];
    const int*   u1d = (const int*)d_in[8];
    const float* item_emb = (const float*)d_in[15];
    const float* fc_w   = (const float*)d_in[16];
    const float* attn_l = (const float*)d_in[17];
    const float* attn_r = (const float*)d_in[18];
    const float* conv_b = (const float*)d_in[19];
    const float* r_w1 = (const float*)d_in[20];
    const float* r_b1 = (const float*)d_in[21];
    const float* r_w2 = (const float*)d_in[22];
    const float* r_b2 = (const float*)d_in[23];
    const float* gran_w = (const float*)d_in[24];

    const int nE1 = in_sizes[1];   // 600000
    const int nE3 = in_sizes[7];   // 200000
    const int nEt = nE1 + nE3;
    const int ND  = N1 + N2;       // combined dst domain

    float* ws = (float*)d_ws;
    // --- zero region (one memset): mean1 | mean2 | cnt (combined)
    float* mean1 = ws;
    float* mean2 = mean1 + EMB;
    int*   cnt   = (int*)(mean2 + EMB);      // ND
    size_t zeroN = 2 * EMB + ND;
    // --- non-zeroed scratch (keep 16B alignment for the float4 arrays)
    int*   off   = cnt + ND;                 // ND+1 (padded to ND+4)
    int*   cur   = off + ND + 4;             // ND
    int*   part  = cur + ND;                 // 128 (need 118)
    int*   esrc  = part + 128;               // nEt (800000, %4==0)
    float* fs0   = (float*)(esrc + nEt);     // N1*128
    float* fs3   = fs0 + (size_t)N1 * EMB;   // N1*128
    float* el0   = fs3 + (size_t)N1 * EMB;   // N1*8
    float* er0   = el0 + (size_t)N1 * NH;    // N1*8
    float* el3   = er0 + (size_t)N1 * NH;    // N1*8
    float* val1  = el3 + (size_t)N1 * NH;    // N1*128
    float* val2  = val1 + (size_t)N1 * EMB;  // N2*128

    hipMemsetAsync(ws, 0, zeroN * sizeof(float), stream);

    // features + attention dots (LDS-staged weights)
    k_feat64<<<(N1 + TILE - 1) / TILE, 256, 0, stream>>>(
        item_emb, item_ids, fc_w, attn_l, attn_r, fs0, fs3, el0, er0, el3);

    // merged CSR build over combined dst domain
    const int nch = (ND + 1023) / 1024;      // 118
    k_count2<<<(nEt + 255) / 256, 256, 0, stream>>>(s1d, nE1, u1d, nE3, cnt);
    k_scan_partial<<<nch, 256, 0, stream>>>(cnt, ND, part);
    k_scan_mid<<<1, 256, 0, stream>>>(part, nch);
    k_scan_final<<<nch, 256, 0, stream>>>(cnt, part, ND, nEt, off, cur);
    k_scatter2<<<(nEt + 255) / 256, 256, 0, stream>>>(s1s, s1d, nE1,
                                                      u1s, u1d, nE3, cur, esrc);

    // merged pull aggregation (writes fully assembled rows)
    k_agg<<<ND / 4, 256, 0, stream>>>(off, esrc, el0, er0, fs0, el3, fs3,
                                      item_emb, item_ids, conv_b, val1, val2);

    // hidden MLP + column-sum reduction
    k_mlp64<<<(N1 + TILE - 1) / TILE, 256, 0, stream>>>(
        val1, N1, r_w1 + 0 * EMB * EMB, r_b1 + 0 * EMB, mean1);
    k_mlp64<<<(N2 + TILE - 1) / TILE, 256, 0, stream>>>(
        val2, N2, r_w1 + 1 * EMB * EMB, r_b1 + 1 * EMB, mean2);

    k_final<<<1, 128, 0, stream>>>(mean1, mean2, conv_b, r_w1, r_b1, r_w2, r_b2,
                                   gran_w, (float*)d_out);
}